// Round 3
// baseline (3297.150 us; speedup 1.0000x reference)
//
#include <hip/hip_runtime.h>
#include <hip/hip_bf16.h>

typedef unsigned short u16;
typedef unsigned int u32;
typedef short s8v __attribute__((ext_vector_type(8)));
typedef float f32x4 __attribute__((ext_vector_type(4)));

#define kT 64
#define kB 4
#define kH 512
#define kC 4096
#define kG 16384
#define kRows 256

__device__ __forceinline__ float b2f(u16 u) { return __builtin_bit_cast(float, ((u32)u) << 16); }
__device__ __forceinline__ u16 f2b(float f) {
  u32 x = __builtin_bit_cast(u32, f);
  return (u16)((x + 0x7fffu + ((x >> 16) & 1u)) >> 16);
}
__device__ __forceinline__ u32 pk2(float lo, float hi) {
  return (u32)f2b(lo) | ((u32)f2b(hi) << 16);
}
__device__ __forceinline__ float sigm(float x) { return 1.f / (1.f + __expf(-x)); }
__device__ __forceinline__ float tanh_(float x) { return 2.f / (1.f + __expf(-2.f * x)) - 1.f; }
__device__ __forceinline__ float clip3(float x) { return fminf(fmaxf(x, -3.f), 3.f); }

// ---------------- diagnostics canary ----------------
__global__ void canary(float* out, float v) { out[0] = v; }

// ---------------- fp32 -> bf16 conversion (Wp) ----------------
__global__ void cvt_f32_bf16(const float* __restrict__ src, u16* __restrict__ dst, int n4) {
  int i = blockIdx.x * blockDim.x + threadIdx.x;
  int stride = gridDim.x * blockDim.x;
  for (; i < n4; i += stride) {
    float4 v = ((const float4*)src)[i];
    ushort4 o;
    o.x = f2b(v.x); o.y = f2b(v.y); o.z = f2b(v.z); o.w = f2b(v.w);
    ((ushort4*)dst)[i] = o;
  }
}

// ---------------- pi = A @ W^T + bias  (MFMA bf16, f32 out) ----------------
// A: [256][512] per dir (f32 if a_is_f32 else bf16), W: [2][16384][512] f32 (NxK)
// bias: [2][16384] f32.  Pi: [2][256][16384] f32
__global__ __launch_bounds__(256) void gemm_pi(const void* __restrict__ A0,
                                               unsigned long long adstride, int a_is_f32,
                                               const float* __restrict__ W,
                                               const float* __restrict__ bias,
                                               float* __restrict__ Pi) {
  int nt = blockIdx.x;   // 0..255 (N tiles of 64)
  int mt = blockIdx.y;   // 0..3   (M tiles of 64)
  int dir = blockIdx.z;  // 0..1
  const float* Bm = W + (size_t)dir * kG * kH + (size_t)nt * 64 * kH;
  const float* bsd = bias + (size_t)dir * kG;
  float* out = Pi + (size_t)dir * kRows * kG;

  __shared__ u16 At[64][40];
  __shared__ u16 Bt[64][40];

  int t = threadIdx.x;
  int w = t >> 6, l = t & 63;
  f32x4 acc[4];
#pragma unroll
  for (int i = 0; i < 4; ++i) acc[i] = (f32x4){0.f, 0.f, 0.f, 0.f};

  int lr = t >> 2, lc = (t & 3) * 8;
  for (int k0 = 0; k0 < kH; k0 += 32) {
    __syncthreads();
    if (a_is_f32) {
      const float* A = (const float*)A0 + (size_t)dir * adstride;
      float4 a0 = *(const float4*)&A[(size_t)(mt * 64 + lr) * kH + k0 + lc];
      float4 a1 = *(const float4*)&A[(size_t)(mt * 64 + lr) * kH + k0 + lc + 4];
      *(uint2*)&At[lr][lc] = (uint2){pk2(a0.x, a0.y), pk2(a0.z, a0.w)};
      *(uint2*)&At[lr][lc + 4] = (uint2){pk2(a1.x, a1.y), pk2(a1.z, a1.w)};
    } else {
      const u16* A = (const u16*)A0 + (size_t)dir * adstride;
      *(uint4*)&At[lr][lc] = *(const uint4*)&A[(size_t)(mt * 64 + lr) * kH + k0 + lc];
    }
    {
      float4 b0 = *(const float4*)&Bm[(size_t)lr * kH + k0 + lc];
      float4 b1 = *(const float4*)&Bm[(size_t)lr * kH + k0 + lc + 4];
      *(uint2*)&Bt[lr][lc] = (uint2){pk2(b0.x, b0.y), pk2(b0.z, b0.w)};
      *(uint2*)&Bt[lr][lc + 4] = (uint2){pk2(b1.x, b1.y), pk2(b1.z, b1.w)};
    }
    __syncthreads();
    int ar = w * 16 + (l & 15), k8 = (l >> 4) * 8;
    s8v af = *(const s8v*)&At[ar][k8];
#pragma unroll
    for (int cg = 0; cg < 4; ++cg) {
      s8v bf = *(const s8v*)&Bt[cg * 16 + (l & 15)][k8];
      acc[cg] = __builtin_amdgcn_mfma_f32_16x16x32_bf16(af, bf, acc[cg], 0, 0, 0);
    }
  }
#pragma unroll
  for (int cg = 0; cg < 4; ++cg) {
    int col = nt * 64 + cg * 16 + (l & 15);
    float bv = bsd[col];
#pragma unroll
    for (int r = 0; r < 4; ++r) {
      int row = mt * 64 + w * 16 + (l >> 4) * 4 + r;
      out[(size_t)row * kG + col] = acc[cg][r] + bv;
    }
  }
}

// ---------------- two-level per-dir grid barrier (128 blocks) ----------------
// bard[0..15]: group counters (8 blocks each), bard[16]: root, bard[32]: flag
__device__ __forceinline__ void gbar(u32* bard, u32 e) {
  __syncthreads();
  if (threadIdx.x == 0) {
    __builtin_amdgcn_fence(__ATOMIC_RELEASE, "agent");
    u32 g = blockIdx.x & 15u;
    u32 old = __hip_atomic_fetch_add(bard + g, 1u, __ATOMIC_RELAXED, __HIP_MEMORY_SCOPE_AGENT);
    if ((old & 7u) == 7u) {
      u32 r = __hip_atomic_fetch_add(bard + 16, 1u, __ATOMIC_RELAXED, __HIP_MEMORY_SCOPE_AGENT);
      if ((r & 15u) == 15u) {
        __hip_atomic_store(bard + 32, e, __ATOMIC_RELAXED, __HIP_MEMORY_SCOPE_AGENT);
      }
    }
    while (__hip_atomic_load(bard + 32, __ATOMIC_RELAXED, __HIP_MEMORY_SCOPE_AGENT) < e) {
      __builtin_amdgcn_s_sleep(1);
    }
    __builtin_amdgcn_fence(__ATOMIC_ACQUIRE, "agent");
  }
  __syncthreads();
}

__device__ __forceinline__ int swz(int kgrp, int key) {
  return (kgrp & ~7) | ((kgrp ^ key) & 7);
}

// ---------------- persistent bi-dir LSTM layer, Ws in LDS ----------------
// 256 blocks x 256 thr. dir = blk>>7. Block owns cells [bid*32, bid*32+32)
// (phase 1, Ws slice in LDS) and proj rows [bid*4, bid*4+4) (phase 2).
__global__ __launch_bounds__(256, 1) void lstm_layer(
    const float* __restrict__ pi,   // [2][256][16384] f32 (bias folded)
    const float* __restrict__ Ws,   // [2][16384][512] f32
    const u16* __restrict__ Wp,     // [2][512][4096] bf16
    const int* __restrict__ mask,   // [4][64]
    const float* __restrict__ skip, // [2][4][64][512] f32
    float* __restrict__ outf,       // [2][4][64][512] f32
    u16* __restrict__ outb,         // [2][256][512] bf16
    float* __restrict__ outfin,     // [4][64][1024] f32
    float* __restrict__ hg,         // [2][4][512] f32 (zeroed)
    u16* __restrict__ hb,           // [2][4][512] bf16 (zeroed)
    u16* __restrict__ actg,         // [2][4][4096] bf16
    u32* __restrict__ bar,          // [2][64] u32 (zeroed)
    int has_skip) {
  __shared__ u16 wlds[128 * 512];        // 128 KiB: [R=g*32+jj][512] swizzled
  __shared__ u16 h_sh[4 * 512];          // 4 KiB, swizzled
  __shared__ float gates_sh[4][32][4];   // [gate][j][b]
  __shared__ float p2[4][16][4];         // [wave][b(col)][pr(reg)]

  int blk = blockIdx.x;
  int dir = blk >> 7;
  int bid = blk & 127;
  int t = threadIdx.x;
  int wv = t >> 6, lane = t & 63;
  int j0 = bid * 32;

  const float* wsd = Ws + (size_t)dir * kG * kH;
  const u16* wpd = Wp + (size_t)dir * kH * kC;
  const float* pid = pi + (size_t)dir * kRows * kG;
  float* hgd = hg + dir * (4 * kH);
  u16* hbd = hb + dir * (4 * kH);
  u16* actd = actg + dir * (4 * kC);
  u32* bard = bar + dir * 64;

  // ---- one-time: load Ws slice -> LDS (f32->bf16, swizzled) ----
  {
    int R = t >> 1, kh = t & 1;
    int g = R >> 5, jj = R & 31;
    const float* src = wsd + ((size_t)g * kC + j0 + jj) * kH;
#pragma unroll 4
    for (int kb = 0; kb < 32; ++kb) {
      int kgrp = kh * 32 + kb;
      float4 a = *(const float4*)(src + kgrp * 8);
      float4 b = *(const float4*)(src + kgrp * 8 + 4);
      uint4 o = {pk2(a.x, a.y), pk2(a.z, a.w), pk2(b.x, b.y), pk2(b.z, b.w)};
      *(uint4*)&wlds[R * 512 + swz(kgrp, R) * 8] = o;
    }
  }
  float c_reg = 0.f;  // cell state for (j = t>>2, b = t&3), threads 0..127
  __syncthreads();

  int col = lane & 15, k8 = lane >> 4;
  u32 e = 0;
  for (int s = 0; s < kT; ++s) {
    int ts = dir ? (kT - 1 - s) : s;

    // ---- stage h (bf16) into swizzled LDS ----
    {
      int b = t >> 6, kgrp = t & 63;
      uint4 v = *(const uint4*)&hbd[b * kH + kgrp * 8];
      *(uint4*)&h_sh[b * 512 + swz(kgrp, b) * 8] = v;
    }
    __syncthreads();

    // ---- phase 1: gates for this block's 32 cells; wave wv = gate ----
    f32x4 acc0 = {0.f, 0.f, 0.f, 0.f}, acc1 = {0.f, 0.f, 0.f, 0.f};
    {
      int R0 = wv * 32 + col;
#pragma unroll
      for (int kt = 0; kt < 16; ++kt) {
        int kgrp = kt * 4 + k8;
        s8v bf = *(const s8v*)&h_sh[(col & 3) * 512 + swz(kgrp, col) * 8];
        int sw = swz(kgrp, R0) * 8;  // R1 = R0+16: same low-3 XOR
        s8v a0 = *(const s8v*)&wlds[R0 * 512 + sw];
        s8v a1 = *(const s8v*)&wlds[(R0 + 16) * 512 + sw];
        acc0 = __builtin_amdgcn_mfma_f32_16x16x32_bf16(a0, bf, acc0, 0, 0, 0);
        acc1 = __builtin_amdgcn_mfma_f32_16x16x32_bf16(a1, bf, acc1, 0, 0, 0);
      }
    }
    if (col < 4) {
      int jr = (lane >> 4) * 4;
      const float* pp = pid + (size_t)(col * kT + ts) * kG + wv * kC + j0 + jr;
      float4 p0 = *(const float4*)pp;
      float4 p1 = *(const float4*)(pp + 16);
      gates_sh[wv][jr + 0][col] = acc0[0] + p0.x;
      gates_sh[wv][jr + 1][col] = acc0[1] + p0.y;
      gates_sh[wv][jr + 2][col] = acc0[2] + p0.z;
      gates_sh[wv][jr + 3][col] = acc0[3] + p0.w;
      gates_sh[wv][16 + jr + 0][col] = acc1[0] + p1.x;
      gates_sh[wv][16 + jr + 1][col] = acc1[1] + p1.y;
      gates_sh[wv][16 + jr + 2][col] = acc1[2] + p1.z;
      gates_sh[wv][16 + jr + 3][col] = acc1[3] + p1.w;
    }
    __syncthreads();

    // ---- cell update (threads 0..127: j = t>>2, b = t&3) ----
    if (t < 128) {
      int j = t >> 2, b = t & 3;
      float gi = gates_sh[0][j][b], gf = gates_sh[1][j][b];
      float gg = gates_sh[2][j][b], go = gates_sh[3][j][b];
      float cn = clip3(sigm(gi) * tanh_(gg) + sigm(gf) * c_reg);
      if (mask[b * kT + ts] > 0) c_reg = cn;
      actd[b * kC + j0 + j] = f2b(sigm(go) * tanh_(cn));
    }
    gbar(bard, ++e);

    // ---- phase 2: h = clip(act @ Wp^T), k-split over 4 waves ----
    {
      int p0r = bid * 4;
      const u16* wrow = wpd + (size_t)(p0r + (col & 3)) * kC + k8 * 8;
      const u16* arow = actd + (size_t)(col & 3) * kC + k8 * 8;
      f32x4 pacc = {0.f, 0.f, 0.f, 0.f};
#pragma unroll 8
      for (int kt = 0; kt < 32; ++kt) {
        int kk = (wv * 32 + kt) * 32;
        s8v af = *(const s8v*)(wrow + kk);
        s8v bf = *(const s8v*)(arow + kk);
        pacc = __builtin_amdgcn_mfma_f32_16x16x32_bf16(af, bf, pacc, 0, 0, 0);
      }
      if (lane < 16) {
#pragma unroll
        for (int r = 0; r < 4; ++r) p2[wv][lane][r] = pacc[r];
      }
    }
    __syncthreads();
    if (t < 16) {
      int b = t >> 2, pr = t & 3;
      float hv = clip3(p2[0][b][pr] + p2[1][b][pr] + p2[2][b][pr] + p2[3][b][pr]);
      int p = bid * 4 + pr;
      int valid = mask[b * kT + ts] > 0;
      float hold = hgd[b * kH + p];
      float hnew = valid ? hv : hold;
      float ov = valid ? hv : 0.f;
      hgd[b * kH + p] = hnew;
      hbd[b * kH + p] = f2b(hnew);
      size_t oidx = (size_t)((dir * 4 + b) * kT + ts) * kH + p;
      outf[oidx] = ov;
      outb[(size_t)(dir * kRows + b * kT + ts) * kH + p] = f2b(ov);
      outfin[(size_t)(b * kT + ts) * 1024 + dir * kH + p] = ov + (has_skip ? skip[oidx] : 0.f);
    }
    gbar(bard, ++e);
  }
}

// ---------------- host launch ----------------
extern "C" void kernel_launch(void* const* d_in, const int* in_sizes, int n_in,
                              void* d_out, int out_size, void* d_ws, size_t ws_size,
                              hipStream_t stream) {
  (void)in_sizes; (void)n_in; (void)out_size;
  const float* inputs = (const float*)d_in[0];
  const int* maskp = (const int*)d_in[1];
  const float* Wi = (const float*)d_in[2];
  const float* Wsrc = (const float*)d_in[3];
  const float* bs = (const float*)d_in[4];
  const float* Wp = (const float*)d_in[5];
  float* out = (float*)d_out;

  char* w = (char*)d_ws;
  size_t off = 0;
  auto alloc = [&](size_t bytes) { size_t o = off; off = (off + bytes + 255) & ~(size_t)255; return o; };
  size_t o_bar = alloc(2 * 2 * 64 * 4);              // [layer][dir][64] u32
  size_t o_hg = alloc((size_t)2 * 2 * 4 * kH * 4);   // [layer][dir][4][512] f32
  size_t o_hb = alloc((size_t)2 * 2 * 4 * kH * 2);   // [layer][dir][4][512] bf16
  size_t zero_bytes = off;
  size_t o_act = alloc((size_t)2 * 4 * kC * 2);
  size_t o_wp = alloc((size_t)2 * kH * kC * 2);
  size_t o_pi = alloc((size_t)2 * kRows * kG * 4);   // f32 now
  size_t o_o0f = alloc((size_t)2 * 4 * kT * kH * 4);
  size_t o_o0b = alloc((size_t)2 * kRows * kH * 2);
  size_t o_o1f = alloc((size_t)2 * 4 * kT * kH * 4);
  size_t o_o1b = alloc((size_t)2 * kRows * kH * 2);
  if (ws_size < off) {  // canary: absmax ~1e6 diagnoses insufficient workspace
    canary<<<1, 1, 0, stream>>>(out, 1.0e6f);
    return;
  }

  hipMemsetAsync(d_ws, 0, zero_bytes, stream);

  u16* wpb = (u16*)(w + o_wp);
  float* pib = (float*)(w + o_pi);

  for (int l = 0; l < 2; ++l) {
    cvt_f32_bf16<<<1024, 256, 0, stream>>>(Wp + (size_t)l * 2 * kH * kC, wpb, 2 * kH * kC / 4);

    const void* A0 = (l == 0) ? (const void*)inputs : (const void*)(w + o_o0b);
    unsigned long long adstr = (l == 0) ? 0ull : (unsigned long long)(kRows * kH);
    int a_is_f32 = (l == 0) ? 1 : 0;
    gemm_pi<<<dim3(256, 4, 2), 256, 0, stream>>>(A0, adstr, a_is_f32,
                                                 Wi + (size_t)l * 2 * kG * kH,
                                                 bs + (size_t)l * 2 * kG, pib);

    const float* pi_c = pib;
    const float* ws_c = Wsrc + (size_t)l * 2 * kG * kH;
    const u16* wp_c = wpb;
    const int* mask_c = maskp;
    const float* skip_c = (const float*)(w + o_o0f);
    float* outf_c = (float*)(w + (l ? o_o1f : o_o0f));
    u16* outb_c = (u16*)(w + (l ? o_o1b : o_o0b));
    float* fin_c = out + (size_t)l * 4 * kT * 1024;
    float* hg_c = (float*)(w + o_hg + (size_t)l * 2 * 4 * kH * 4);
    u16* hb_c = (u16*)(w + o_hb + (size_t)l * 2 * 4 * kH * 2);
    u16* act_c = (u16*)(w + o_act);
    u32* bar_c = (u32*)(w + o_bar + (size_t)l * 2 * 64 * 4);
    int has_skip = l;

    void* args[] = {&pi_c, &ws_c, &wp_c, &mask_c, &skip_c, &outf_c, &outb_c,
                    &fin_c, &hg_c, &hb_c, &act_c, &bar_c, &has_skip};
    hipError_t err = hipLaunchCooperativeKernel((const void*)lstm_layer, dim3(256),
                                                dim3(256), args, 0, stream);
    if (err != hipSuccess) {  // canary: absmax ~2e6 diagnoses coop-launch rejection
      canary<<<1, 1, 0, stream>>>(out, 2.0e6f);
      return;
    }
  }
}